// Round 1
// baseline (3170.327 us; speedup 1.0000x reference)
//
#include <hip/hip_runtime.h>

#define SCALE 0.95f

// ---------------- Kernel 1: first conv 3->16, 3x3, stride 2, pad 1, ReLU ----
__global__ __launch_bounds__(256) void k_first(
    const float* __restrict__ x, const float* __restrict__ w,
    const float* __restrict__ bias, float* __restrict__ h) {
  const int b = blockIdx.x;
  const int t = threadIdx.x;
  __shared__ float lx[3 * 34 * 35];   // zero-padded input, row stride 35 (bank-friendly)
  __shared__ float lw[27 * 16];       // [ci*9+k][co]
  __shared__ float lb[16];
  for (int i = t; i < 3 * 34 * 35; i += 256) lx[i] = 0.f;
  if (t < 16) lb[t] = bias[t];
  for (int i = t; i < 432; i += 256) {
    int co = i / 27, r = i - co * 27;
    lw[r * 16 + co] = w[i];
  }
  __syncthreads();
  const float4* xb = (const float4*)(x + (size_t)b * 3072);
  for (int i = t; i < 768; i += 256) {
    float4 v = xb[i];
    int e4 = i * 4;
    int ci = e4 >> 10, rem = e4 & 1023, iy = rem >> 5, ix = rem & 31;
    float* d = &lx[ci * 1190 + (iy + 1) * 35 + (ix + 1)];
    d[0] = v.x; d[1] = v.y; d[2] = v.z; d[3] = v.w;
  }
  __syncthreads();
  const int oy = t >> 4, ox = t & 15;
  float acc[16];
#pragma unroll
  for (int c = 0; c < 16; ++c) acc[c] = 0.f;
#pragma unroll
  for (int ci = 0; ci < 3; ++ci) {
    const float* base = &lx[ci * 1190 + (2 * oy) * 35 + 2 * ox];
    float win[9];
#pragma unroll
    for (int dy = 0; dy < 3; ++dy)
#pragma unroll
      for (int dx = 0; dx < 3; ++dx) win[dy * 3 + dx] = base[dy * 35 + dx];
#pragma unroll
    for (int k = 0; k < 9; ++k) {
      const float4* wv = (const float4*)&lw[(ci * 9 + k) * 16];
      float f = win[k];
#pragma unroll
      for (int q = 0; q < 4; ++q) {
        float4 ww = wv[q];
        acc[q * 4 + 0] += f * ww.x;
        acc[q * 4 + 1] += f * ww.y;
        acc[q * 4 + 2] += f * ww.z;
        acc[q * 4 + 3] += f * ww.w;
      }
    }
  }
  float* hb = h + (size_t)b * 4096;
#pragma unroll
  for (int c = 0; c < 16; ++c) {
    float v = acc[c] + lb[c];
    hb[c * 256 + t] = v > 0.f ? v : 0.f;
  }
}

// -------- Kernel 2: fused gate(argmax, fp64) + selected expert conv --------
__global__ __launch_bounds__(256) void k_route(
    const float* __restrict__ hin, const float* __restrict__ gw,
    const float* __restrict__ ew, const float* __restrict__ eb,
    float* __restrict__ hout) {
  const int b = blockIdx.x;
  const int t = threadIdx.x;
  __shared__ float lh[16 * 18 * 18];  // zero-padded h, row stride 18
  __shared__ float lw[2304];          // [ci*9+k][co]
  __shared__ float lb[16];
  __shared__ double wred[4][6];
  __shared__ int sel;
  for (int i = t; i < 5184; i += 256) lh[i] = 0.f;
  __syncthreads();
  const float4* hb4 = (const float4*)(hin + (size_t)b * 4096);
  for (int i = t; i < 1024; i += 256) {
    float4 v = hb4[i];
    int e4 = i * 4;
    int ci = e4 >> 8, rem = e4 & 255, y = rem >> 4, x = rem & 15;
    float* d = &lh[ci * 324 + (y + 1) * 18 + (x + 1)];
    d[0] = v.x; d[1] = v.y; d[2] = v.z; d[3] = v.w;
  }
  __syncthreads();
  // ---- gate: argmax of 6 logits (softmax monotone; top-1 weight == SCALE) ----
  {
    const int gci = t >> 4, gy = t & 15;
    const float* hrow = &lh[gci * 324 + (gy + 1) * 18 + 1];
    float hv[16];
#pragma unroll
    for (int xx = 0; xx < 16; ++xx) hv[xx] = hrow[xx];
    double s[6];
#pragma unroll
    for (int e = 0; e < 6; ++e) s[e] = 0.0;
#pragma unroll
    for (int e = 0; e < 6; ++e) {
      const float4* wr = (const float4*)(gw + (size_t)e * 4096 + t * 16);
#pragma unroll
      for (int q = 0; q < 4; ++q) {
        float4 wv = wr[q];
        s[e] += (double)hv[q * 4 + 0] * wv.x + (double)hv[q * 4 + 1] * wv.y +
                (double)hv[q * 4 + 2] * wv.z + (double)hv[q * 4 + 3] * wv.w;
      }
    }
#pragma unroll
    for (int off = 32; off > 0; off >>= 1) {
#pragma unroll
      for (int e = 0; e < 6; ++e) s[e] += __shfl_down(s[e], off);
    }
    if ((t & 63) == 0) {
#pragma unroll
      for (int e = 0; e < 6; ++e) wred[t >> 6][e] = s[e];
    }
  }
  __syncthreads();
  if (t == 0) {
    double best = -1.0e300; int bi = 0;
#pragma unroll
    for (int e = 0; e < 6; ++e) {
      double v = wred[0][e] + wred[1][e] + wred[2][e] + wred[3][e];
      if (v > best) { best = v; bi = e; }  // strict > : first index on ties
    }
    sel = bi;
  }
  __syncthreads();
  const int e = sel;
  for (int i = t; i < 2304; i += 256) {
    int co = i / 144, r = i - co * 144;
    lw[r * 16 + co] = ew[(size_t)e * 2304 + i];
  }
  if (t < 16) lb[t] = eb[e * 16 + t];
  __syncthreads();
  // ---- expert conv 16->16, 3x3, s1, p1; ReLU; *0.95 ----
  const int y = t >> 4, x = t & 15;
  float acc[16];
#pragma unroll
  for (int c = 0; c < 16; ++c) acc[c] = 0.f;
#pragma unroll
  for (int ci = 0; ci < 16; ++ci) {
    const float* base = &lh[ci * 324 + y * 18 + x];
    float win[9];
#pragma unroll
    for (int dy = 0; dy < 3; ++dy)
#pragma unroll
      for (int dx = 0; dx < 3; ++dx) win[dy * 3 + dx] = base[dy * 18 + dx];
#pragma unroll
    for (int k = 0; k < 9; ++k) {
      const float4* wv = (const float4*)&lw[(ci * 9 + k) * 16];
      float f = win[k];
#pragma unroll
      for (int q = 0; q < 4; ++q) {
        float4 ww = wv[q];
        acc[q * 4 + 0] += f * ww.x;
        acc[q * 4 + 1] += f * ww.y;
        acc[q * 4 + 2] += f * ww.z;
        acc[q * 4 + 3] += f * ww.w;
      }
    }
  }
  float* ho = hout + (size_t)b * 4096;
#pragma unroll
  for (int c = 0; c < 16; ++c) {
    float v = acc[c] + lb[c];
    v = v > 0.f ? v : 0.f;
    ho[c * 256 + t] = SCALE * v;
  }
}

// ---- Kernel 3: last conv 16->8 s2 p1 + ReLU + maxpool2 + fc1 + ReLU + fc2 ----
__global__ __launch_bounds__(64) void k_tail(
    const float* __restrict__ hin, const float* __restrict__ lwg,
    const float* __restrict__ lbg, const float* __restrict__ f1w,
    const float* __restrict__ f1b, const float* __restrict__ f2w,
    const float* __restrict__ f2b, float* __restrict__ out) {
  const int b = blockIdx.x;
  const int t = threadIdx.x;
  __shared__ float lh[16 * 18 * 18];
  __shared__ float lw[1152];   // [ci*9+k][co], co<8
  __shared__ float lb[8];
  __shared__ float pool[128];
  __shared__ float f1[16];
  for (int i = t; i < 5184; i += 64) lh[i] = 0.f;
  if (t < 8) lb[t] = lbg[t];
  for (int i = t; i < 1152; i += 64) {
    int co = i / 144, r = i - co * 144;
    lw[r * 8 + co] = lwg[i];
  }
  __syncthreads();
  const float4* hb4 = (const float4*)(hin + (size_t)b * 4096);
  for (int i = t; i < 1024; i += 64) {
    float4 v = hb4[i];
    int e4 = i * 4;
    int ci = e4 >> 8, rem = e4 & 255, y = rem >> 4, x = rem & 15;
    float* d = &lh[ci * 324 + (y + 1) * 18 + (x + 1)];
    d[0] = v.x; d[1] = v.y; d[2] = v.z; d[3] = v.w;
  }
  __syncthreads();
  const int oy = t >> 3, ox = t & 7;
  float acc[8];
#pragma unroll
  for (int c = 0; c < 8; ++c) acc[c] = 0.f;
#pragma unroll
  for (int ci = 0; ci < 16; ++ci) {
    const float* base = &lh[ci * 324 + (2 * oy) * 18 + 2 * ox];
    float win[9];
#pragma unroll
    for (int dy = 0; dy < 3; ++dy)
#pragma unroll
      for (int dx = 0; dx < 3; ++dx) win[dy * 3 + dx] = base[dy * 18 + dx];
#pragma unroll
    for (int k = 0; k < 9; ++k) {
      const float4* wv = (const float4*)&lw[(ci * 9 + k) * 8];
      float f = win[k];
#pragma unroll
      for (int q = 0; q < 2; ++q) {
        float4 ww = wv[q];
        acc[q * 4 + 0] += f * ww.x;
        acc[q * 4 + 1] += f * ww.y;
        acc[q * 4 + 2] += f * ww.z;
        acc[q * 4 + 3] += f * ww.w;
      }
    }
  }
  // ReLU + 2x2 maxpool via shuffles: lane = oy*8+ox; partners at ^1 (x), ^8 (y)
#pragma unroll
  for (int c = 0; c < 8; ++c) {
    float v = acc[c] + lb[c];
    v = v > 0.f ? v : 0.f;
    float m = fmaxf(v, __shfl_xor(v, 1));
    m = fmaxf(m, __shfl_xor(m, 8));
    if (((oy | ox) & 1) == 0) pool[c * 16 + (oy >> 1) * 4 + (ox >> 1)] = m;
  }
  __syncthreads();
  if (t < 16) {
    float a = f1b[t];
    const float* wr = f1w + t * 128;
#pragma unroll 8
    for (int j = 0; j < 128; ++j) a += pool[j] * wr[j];
    f1[t] = a > 0.f ? a : 0.f;
  }
  __syncthreads();
  if (t < 10) {
    float a = f2b[t];
    const float* wr = f2w + t * 16;
#pragma unroll
    for (int j = 0; j < 16; ++j) a += f1[j] * wr[j];
    out[(size_t)b * 10 + t] = a;
  }
}

extern "C" void kernel_launch(void* const* d_in, const int* in_sizes, int n_in,
                              void* d_out, int out_size, void* d_ws, size_t ws_size,
                              hipStream_t stream) {
  const float* x   = (const float*)d_in[0];
  const float* w1  = (const float*)d_in[1];
  const float* b1  = (const float*)d_in[2];
  const float* ew  = (const float*)d_in[3];
  const float* eb  = (const float*)d_in[4];
  const float* gw  = (const float*)d_in[5];
  const float* lwg = (const float*)d_in[6];
  const float* lbg = (const float*)d_in[7];
  const float* f1w = (const float*)d_in[8];
  const float* f1b = (const float*)d_in[9];
  const float* f2w = (const float*)d_in[10];
  const float* f2b = (const float*)d_in[11];

  float* hA = (float*)d_ws;                       // 8192*4096 fp32 = 128 MiB
  float* hB = hA + (size_t)8192 * 4096;           // 128 MiB
  float* outp = (float*)d_out;

  k_first<<<8192, 256, 0, stream>>>(x, w1, b1, hA);
  float* cur = hA; float* nxt = hB;
  for (int it = 0; it < 4; ++it) {
    k_route<<<8192, 256, 0, stream>>>(cur, gw, ew, eb, nxt);
    float* tmp = cur; cur = nxt; nxt = tmp;
  }
  k_tail<<<8192, 64, 0, stream>>>(cur, lwg, lbg, f1w, f1b, f2w, f2b, outp);
}

// Round 2
// 1112.174 us; speedup vs baseline: 2.8506x; 2.8506x over previous
//
#include <hip/hip_runtime.h>

#define SCALE 0.95f

// ---------------- Kernel 1: first conv 3->16, 3x3, stride 2, pad 1, ReLU ----
__global__ __launch_bounds__(256) void k_first(
    const float* __restrict__ x, const float* __restrict__ w,
    const float* __restrict__ bias, float* __restrict__ h) {
  const int b = blockIdx.x;
  const int t = threadIdx.x;
  __shared__ float lx[3 * 34 * 35];   // zero-padded input, row stride 35
  __shared__ float lw[27 * 16];       // [ci*9+k][co]
  __shared__ float lb[16];
  for (int i = t; i < 3 * 34 * 35; i += 256) lx[i] = 0.f;
  if (t < 16) lb[t] = bias[t];
  {  // co-major staging: LDS write addr = r*16+co, lanes co-major -> 2-way (free)
    const int co = t & 15, rb = t >> 4;
    for (int r = rb; r < 27; r += 16) lw[r * 16 + co] = w[co * 27 + r];
  }
  __syncthreads();
  const float4* xb = (const float4*)(x + (size_t)b * 3072);
  for (int i = t; i < 768; i += 256) {
    float4 v = xb[i];
    int e4 = i * 4;
    int ci = e4 >> 10, rem = e4 & 1023, iy = rem >> 5, ix = rem & 31;
    float* d = &lx[ci * 1190 + (iy + 1) * 35 + (ix + 1)];
    d[0] = v.x; d[1] = v.y; d[2] = v.z; d[3] = v.w;
  }
  __syncthreads();
  const int oy = t >> 4, ox = t & 15;
  float acc[16];
#pragma unroll
  for (int c = 0; c < 16; ++c) acc[c] = 0.f;
#pragma unroll
  for (int ci = 0; ci < 3; ++ci) {
    const float* base = &lx[ci * 1190 + (2 * oy) * 35 + 2 * ox];
    float win[9];
#pragma unroll
    for (int dy = 0; dy < 3; ++dy)
#pragma unroll
      for (int dx = 0; dx < 3; ++dx) win[dy * 3 + dx] = base[dy * 35 + dx];
#pragma unroll
    for (int k = 0; k < 9; ++k) {
      const float4* wv = (const float4*)&lw[(ci * 9 + k) * 16];
      float f = win[k];
#pragma unroll
      for (int q = 0; q < 4; ++q) {
        float4 ww = wv[q];
        acc[q * 4 + 0] += f * ww.x;
        acc[q * 4 + 1] += f * ww.y;
        acc[q * 4 + 2] += f * ww.z;
        acc[q * 4 + 3] += f * ww.w;
      }
    }
  }
  float* hb = h + (size_t)b * 4096;
#pragma unroll
  for (int c = 0; c < 16; ++c) {
    float v = acc[c] + lb[c];
    hb[c * 256 + t] = v > 0.f ? v : 0.f;
  }
}

// ---- Kernel 2: fused gate(argmax fp64) + selected expert conv (+full tail) --
template <bool TAIL>
__global__ __launch_bounds__(256) void k_route_t(
    const float* __restrict__ hin, const float* __restrict__ gw,
    const float* __restrict__ ew, const float* __restrict__ eb,
    float* __restrict__ hout,
    const float* __restrict__ lwg, const float* __restrict__ lbg,
    const float* __restrict__ f1w, const float* __restrict__ f1b,
    const float* __restrict__ f2w, const float* __restrict__ f2b,
    float* __restrict__ out) {
  const int b = blockIdx.x;
  const int t = threadIdx.x;
  __shared__ float lh[16 * 18 * 18];  // zero-padded h, row stride 18
  __shared__ float lw[2304];          // [ci*9+k][co]
  __shared__ float lb[16];
  __shared__ double wred[4][6];
  __shared__ int sel;
  for (int i = t; i < 5184; i += 256) lh[i] = 0.f;
  __syncthreads();
  const float4* hb4 = (const float4*)(hin + (size_t)b * 4096);
  for (int i = t; i < 1024; i += 256) {
    float4 v = hb4[i];
    int e4 = i * 4;
    int ci = e4 >> 8, rem = e4 & 255, y = rem >> 4, x = rem & 15;
    float* d = &lh[ci * 324 + (y + 1) * 18 + (x + 1)];
    d[0] = v.x; d[1] = v.y; d[2] = v.z; d[3] = v.w;
  }
  __syncthreads();
  // ---- gate: argmax of 6 logits (softmax monotone; top-1 weight == SCALE) ----
  {
    const float* hrow = &lh[(t >> 4) * 324 + ((t & 15) + 1) * 18 + 1];
    float hv[16];
#pragma unroll
    for (int xx = 0; xx < 16; ++xx) hv[xx] = hrow[xx];
    double s[6];
#pragma unroll
    for (int e = 0; e < 6; ++e) s[e] = 0.0;
#pragma unroll
    for (int e = 0; e < 6; ++e) {
      const float4* wr = (const float4*)(gw + (size_t)e * 4096 + t * 16);
#pragma unroll
      for (int qq = 0; qq < 4; ++qq) {
        float4 wv = wr[qq];
        s[e] += (double)hv[qq * 4 + 0] * wv.x + (double)hv[qq * 4 + 1] * wv.y +
                (double)hv[qq * 4 + 2] * wv.z + (double)hv[qq * 4 + 3] * wv.w;
      }
    }
#pragma unroll
    for (int off = 32; off > 0; off >>= 1) {
#pragma unroll
      for (int e = 0; e < 6; ++e) s[e] += __shfl_down(s[e], off);
    }
    if ((t & 63) == 0) {
#pragma unroll
      for (int e = 0; e < 6; ++e) wred[t >> 6][e] = s[e];
    }
  }
  __syncthreads();
  if (t == 0) {
    double best = -1.0e300; int bi = 0;
#pragma unroll
    for (int e = 0; e < 6; ++e) {
      double v = wred[0][e] + wred[1][e] + wred[2][e] + wred[3][e];
      if (v > best) { best = v; bi = e; }  // strict > : first index on ties
    }
    sel = bi;
  }
  __syncthreads();
  const int e = sel;
  // stage expert weights transposed [ci*9+k][co]; co-major lanes -> 2-way free
  {
    const int co = t & 15, rb = t >> 4;  // rb 0..15, 16 r's each... r = rb*9+j
    const float* src = ew + (size_t)e * 2304 + co * 144 + rb * 9;
    float v[9];
#pragma unroll
    for (int j = 0; j < 9; ++j) v[j] = src[j];
#pragma unroll
    for (int j = 0; j < 9; ++j) lw[(rb * 9 + j) * 16 + co] = v[j];
  }
  if (t < 16) lb[t] = eb[e * 16 + t];
  __syncthreads();
  // ---- expert conv 16->16, 3x3, s1, p1; thread = (co-quad q, 2x2 px tile) ---
  const int q = t >> 6;            // wave-uniform co quad
  const int p = t & 63;
  const int ty = p >> 3, tx = p & 7;
  float acc[4][4];                 // [co_j][py*2+px]
#pragma unroll
  for (int j = 0; j < 4; ++j)
#pragma unroll
    for (int pp = 0; pp < 4; ++pp) acc[j][pp] = 0.f;
#pragma unroll
  for (int ci = 0; ci < 16; ++ci) {
    const float* base = &lh[ci * 324 + (2 * ty) * 18 + 2 * tx];
    float win[4][4];
#pragma unroll
    for (int wy = 0; wy < 4; ++wy) {
      float2 a = *(const float2*)&base[wy * 18];
      float2 c = *(const float2*)&base[wy * 18 + 2];
      win[wy][0] = a.x; win[wy][1] = a.y; win[wy][2] = c.x; win[wy][3] = c.y;
    }
#pragma unroll
    for (int dy = 0; dy < 3; ++dy)
#pragma unroll
      for (int dx = 0; dx < 3; ++dx) {
        float4 ww = *(const float4*)&lw[(ci * 9 + dy * 3 + dx) * 16 + q * 4];
#pragma unroll
        for (int py = 0; py < 2; ++py)
#pragma unroll
          for (int px = 0; px < 2; ++px) {
            float f = win[py + dy][px + dx];
            acc[0][py * 2 + px] += f * ww.x;
            acc[1][py * 2 + px] += f * ww.y;
            acc[2][py * 2 + px] += f * ww.z;
            acc[3][py * 2 + px] += f * ww.w;
          }
      }
  }
  float val[4][4];
#pragma unroll
  for (int j = 0; j < 4; ++j) {
    float bj = lb[q * 4 + j];
#pragma unroll
    for (int pp = 0; pp < 4; ++pp) {
      float v = acc[j][pp] + bj;
      v = v > 0.f ? v : 0.f;
      val[j][pp] = SCALE * v;
    }
  }
  if constexpr (!TAIL) {
    float* ho = hout + (size_t)b * 4096;
#pragma unroll
    for (int j = 0; j < 4; ++j) {
      int co = q * 4 + j;
#pragma unroll
      for (int dy = 0; dy < 2; ++dy) {
        float2 v2 = make_float2(val[j][dy * 2 + 0], val[j][dy * 2 + 1]);
        *(float2*)&ho[co * 256 + (2 * ty + dy) * 16 + 2 * tx] = v2;
      }
    }
  } else {
    // ---------- fused tail: write h back to LDS, last conv, pool, fc1, fc2 ---
    __shared__ float lw2[1152];  // [ci*9+k][co<8]
    __shared__ float lb2[8];
    __shared__ float pool[128];
    __shared__ float f1v[16];
    __shared__ float fred[16][8];
    __syncthreads();  // all window reads of old h done
#pragma unroll
    for (int j = 0; j < 4; ++j) {
      int co = q * 4 + j;
#pragma unroll
      for (int dy = 0; dy < 2; ++dy)
#pragma unroll
        for (int dx = 0; dx < 2; ++dx)
          lh[co * 324 + (2 * ty + dy + 1) * 18 + (2 * tx + dx + 1)] =
              val[j][dy * 2 + dx];
    }
    if (t < 128) {  // stage last-conv weights transposed
      const int co = t & 7, rb = t >> 3;
      const float* src = lwg + co * 144 + rb * 9;
      float v[9];
#pragma unroll
      for (int j = 0; j < 9; ++j) v[j] = src[j];
#pragma unroll
      for (int j = 0; j < 9; ++j) lw2[(rb * 9 + j) * 8 + co] = v[j];
    }
    if (t < 8) lb2[t] = lbg[t];
    __syncthreads();
    // last conv 16->8 s2 p1: thread = (co-pair cop, out pixel oy,ox)
    const int cop = t >> 6;
    const int oy = (t & 63) >> 3, ox = t & 7;
    float a2[2] = {0.f, 0.f};
#pragma unroll
    for (int ci = 0; ci < 16; ++ci) {
      const float* base2 = &lh[ci * 324 + (2 * oy) * 18 + 2 * ox];
      float w33[3][3];
#pragma unroll
      for (int dy = 0; dy < 3; ++dy) {
        float2 a = *(const float2*)&base2[dy * 18];
        w33[dy][0] = a.x; w33[dy][1] = a.y; w33[dy][2] = base2[dy * 18 + 2];
      }
#pragma unroll
      for (int dy = 0; dy < 3; ++dy)
#pragma unroll
        for (int dx = 0; dx < 3; ++dx) {
          float2 ww = *(const float2*)&lw2[(ci * 9 + dy * 3 + dx) * 8 + cop * 2];
          float f = w33[dy][dx];
          a2[0] += f * ww.x;
          a2[1] += f * ww.y;
        }
    }
    // ReLU + 2x2 maxpool via shuffles (lane = oy*8+ox): ^1 -> ox, ^8 -> oy
#pragma unroll
    for (int j = 0; j < 2; ++j) {
      int co = cop * 2 + j;
      float v = a2[j] + lb2[co];
      v = v > 0.f ? v : 0.f;
      float m = fmaxf(v, __shfl_xor(v, 1));
      m = fmaxf(m, __shfl_xor(m, 8));
      if (((oy | ox) & 1) == 0) pool[co * 16 + (oy >> 1) * 4 + (ox >> 1)] = m;
    }
    __syncthreads();
    if (t < 128) {  // fc1: 16 rows x 8 segments of 16
      const int r = t & 15, sg = t >> 4;
      const float* wr = f1w + r * 128 + sg * 16;
      const float* pp = pool + sg * 16;
      float a = 0.f;
#pragma unroll
      for (int j = 0; j < 16; ++j) a += pp[j] * wr[j];
      fred[r][sg] = a;
    }
    __syncthreads();
    if (t < 16) {
      float a = f1b[t];
#pragma unroll
      for (int s = 0; s < 8; ++s) a += fred[t][s];
      f1v[t] = a > 0.f ? a : 0.f;
    }
    __syncthreads();
    if (t < 10) {
      float a = f2b[t];
#pragma unroll
      for (int j = 0; j < 16; ++j) a += f1v[j] * f2w[t * 16 + j];
      out[(size_t)b * 10 + t] = a;
    }
  }
}

extern "C" void kernel_launch(void* const* d_in, const int* in_sizes, int n_in,
                              void* d_out, int out_size, void* d_ws, size_t ws_size,
                              hipStream_t stream) {
  const float* x   = (const float*)d_in[0];
  const float* w1  = (const float*)d_in[1];
  const float* b1  = (const float*)d_in[2];
  const float* ew  = (const float*)d_in[3];
  const float* eb  = (const float*)d_in[4];
  const float* gw  = (const float*)d_in[5];
  const float* lwg = (const float*)d_in[6];
  const float* lbg = (const float*)d_in[7];
  const float* f1w = (const float*)d_in[8];
  const float* f1b = (const float*)d_in[9];
  const float* f2w = (const float*)d_in[10];
  const float* f2b = (const float*)d_in[11];

  float* hA = (float*)d_ws;                       // 8192*4096 fp32 = 128 MiB
  float* hB = hA + (size_t)8192 * 4096;           // 128 MiB
  float* outp = (float*)d_out;

  k_first<<<8192, 256, 0, stream>>>(x, w1, b1, hA);
  float* cur = hA; float* nxt = hB;
  for (int it = 0; it < 3; ++it) {
    k_route_t<false><<<8192, 256, 0, stream>>>(cur, gw, ew, eb, nxt,
                                               lwg, lbg, f1w, f1b, f2w, f2b, outp);
    float* tmp = cur; cur = nxt; nxt = tmp;
  }
  k_route_t<true><<<8192, 256, 0, stream>>>(cur, gw, ew, eb, nullptr,
                                            lwg, lbg, f1w, f1b, f2w, f2b, outp);
}

// Round 3
// 910.200 us; speedup vs baseline: 3.4831x; 1.2219x over previous
//
#include <hip/hip_runtime.h>

#define SCALE 0.95f

// ---------- Kernel 0: weight transposes (1 block, runs each launch) --------
__global__ __launch_bounds__(256) void k_prep(
    const float* __restrict__ w1, const float* __restrict__ ew,
    const float* __restrict__ lwg, float* __restrict__ w1t,
    float* __restrict__ ewt, float* __restrict__ lwt) {
  const int t = threadIdx.x;
  for (int i = t; i < 432; i += 256) {          // w1 [16co][27] -> w1t [27][16co]
    int co = i / 27, r = i - co * 27;
    w1t[r * 16 + co] = w1[i];
  }
  for (int i = t; i < 13824; i += 256) {        // ew [6][16co][144] -> ewt [6][16ci][9k][16co]
    int e = i / 2304, r = i - e * 2304;
    int co = r / 144, s = r - co * 144;
    int ci = s / 9, k = s - ci * 9;
    ewt[(e * 16 + ci) * 144 + k * 16 + co] = ew[i];
  }
  for (int i = t; i < 1152; i += 256) {         // lwg [8co][144] -> lwt [144][8co]
    int co = i / 144, s = i - co * 144;
    lwt[s * 8 + co] = lwg[i];
  }
}

// ---------------- Kernel 1: first conv 3->16, 3x3, stride 2, pad 1, ReLU ----
__global__ __launch_bounds__(256, 4) void k_first(
    const float* __restrict__ x, const float* __restrict__ w1t,
    const float* __restrict__ b1, float* __restrict__ h) {
  const int b = blockIdx.x;
  const int t = threadIdx.x;
  __shared__ float lx[3 * 34 * 35];   // zero-padded input, row stride 35
  for (int i = t; i < 396; i += 256) {  // halo only
    int ci = i / 132, r = i - ci * 132;
    int y, xx;
    if (r < 34)       { y = 0;      xx = r; }
    else if (r < 68)  { y = 33;     xx = r - 34; }
    else if (r < 100) { y = r - 67; xx = 0; }
    else              { y = r - 99; xx = 33; }
    lx[ci * 1190 + y * 35 + xx] = 0.f;
  }
  const float4* xb = (const float4*)(x + (size_t)b * 3072);
#pragma unroll
  for (int k = 0; k < 3; ++k) {
    int i = t + k * 256;
    float4 v = xb[i];
    int e4 = i * 4;
    int ci = e4 >> 10, rem = e4 & 1023, iy = rem >> 5, ix = rem & 31;
    float* d = &lx[ci * 1190 + (iy + 1) * 35 + (ix + 1)];
    d[0] = v.x; d[1] = v.y; d[2] = v.z; d[3] = v.w;
  }
  __syncthreads();
  const int oy = t >> 4, ox = t & 15;
  float acc[16] = {};
#pragma unroll
  for (int ci = 0; ci < 3; ++ci) {
    const float* base = &lx[ci * 1190 + (2 * oy) * 35 + 2 * ox];
    float win[9];
#pragma unroll
    for (int dy = 0; dy < 3; ++dy)
#pragma unroll
      for (int dx = 0; dx < 3; ++dx) win[dy * 3 + dx] = base[dy * 35 + dx];
#pragma unroll
    for (int k = 0; k < 9; ++k) {
      const float* wt = w1t + (ci * 9 + k) * 16;   // uniform -> s_load
      float f = win[k];
#pragma unroll
      for (int c = 0; c < 16; ++c) acc[c] += f * wt[c];
    }
  }
  float* hb = h + (size_t)b * 4096;
#pragma unroll
  for (int c = 0; c < 16; ++c) {
    float v = acc[c] + b1[c];
    hb[c * 256 + t] = v > 0.f ? v : 0.f;
  }
}

// ---- Kernel 2: fused gate(argmax fp64) + selected expert conv (+tail) ------
template <bool TAIL>
__global__ __launch_bounds__(256, 4) void k_route_t(
    float* __restrict__ h, const float* __restrict__ gw,
    const float* __restrict__ ewt, const float* __restrict__ eb,
    const float* __restrict__ lwt, const float* __restrict__ lbg,
    const float* __restrict__ f1w, const float* __restrict__ f1b,
    const float* __restrict__ f2w, const float* __restrict__ f2b,
    float* __restrict__ out) {
  const int b = blockIdx.x;
  const int t = threadIdx.x;
  __shared__ float lh[16 * 18 * 18];  // zero-padded h, row stride 18
  __shared__ double wred[4][6];
  // halo zero (disjoint from staged interior; same phase, no barrier between)
  for (int i = t; i < 1088; i += 256) {
    int ci = i / 68, r = i - ci * 68;
    int y, x;
    if (r < 18)      { y = 0;      x = r; }
    else if (r < 36) { y = 17;     x = r - 18; }
    else if (r < 52) { y = r - 35; x = 0; }
    else             { y = r - 51; x = 17; }
    lh[ci * 324 + y * 18 + x] = 0.f;
  }
  // stage h -> LDS, keeping the values in registers for the gate
  float4 hr[4];
  const float4* hb4 = (const float4*)(h + (size_t)b * 4096);
#pragma unroll
  for (int k = 0; k < 4; ++k) {
    int i = t + k * 256;
    hr[k] = hb4[i];
    int e4 = i * 4;
    int ci = e4 >> 8, rem = e4 & 255, y = rem >> 4, x = rem & 15;
    float* d = &lh[ci * 324 + (y + 1) * 18 + (x + 1)];
    d[0] = hr[k].x; d[1] = hr[k].y; d[2] = hr[k].z; d[3] = hr[k].w;
  }
  // gate from registers: thread t owns flat indices 4*(t+256k)+j
  double s[6];
  const float4* g4 = (const float4*)gw;
#pragma unroll 1
  for (int e = 0; e < 6; ++e) {
    double se = 0.0;
#pragma unroll
    for (int k = 0; k < 4; ++k) {
      float4 wv = g4[e * 1024 + t + 256 * k];
      se += (double)hr[k].x * wv.x + (double)hr[k].y * wv.y +
            (double)hr[k].z * wv.z + (double)hr[k].w * wv.w;
    }
    s[e] = se;
  }
#pragma unroll
  for (int off = 32; off > 0; off >>= 1) {
#pragma unroll
    for (int e = 0; e < 6; ++e) s[e] += __shfl_down(s[e], off);
  }
  if ((t & 63) == 0) {
#pragma unroll
    for (int e = 0; e < 6; ++e) wred[t >> 6][e] = s[e];
  }
  __syncthreads();  // h staged + wred ready
  // every thread computes the argmax locally (broadcast LDS reads, no barrier)
  int sel = 0;
  {
    double best = -1.0e300;
#pragma unroll
    for (int e = 0; e < 6; ++e) {
      double v = wred[0][e] + wred[1][e] + wred[2][e] + wred[3][e];
      if (v > best) { best = v; sel = e; }  // strict > : first index on ties
    }
  }
  const int e_s = __builtin_amdgcn_readfirstlane(sel);
  const int q = __builtin_amdgcn_readfirstlane(t >> 6);  // wave-uniform co-quad
  const int p = t & 63;
  const int ty = p >> 3, tx = p & 7;
  // ---- expert conv 16->16, 3x3, s1, p1; weights via SGPR (SMEM pipe) -------
  float acc[4][4] = {};
#pragma unroll
  for (int ci = 0; ci < 16; ++ci) {
    const float* base = &lh[ci * 324 + (2 * ty) * 18 + 2 * tx];
    const float* wbase = ewt + (e_s * 16 + ci) * 144 + q * 4;  // uniform
    float win[4][4];
#pragma unroll
    for (int wy = 0; wy < 4; ++wy) {
      float2 a = *(const float2*)&base[wy * 18];
      float2 c = *(const float2*)&base[wy * 18 + 2];
      win[wy][0] = a.x; win[wy][1] = a.y; win[wy][2] = c.x; win[wy][3] = c.y;
    }
#pragma unroll
    for (int dy = 0; dy < 3; ++dy)
#pragma unroll
      for (int dx = 0; dx < 3; ++dx) {
        const float* wt = wbase + (dy * 3 + dx) * 16;
        float w0 = wt[0], w1_ = wt[1], w2 = wt[2], w3 = wt[3];
#pragma unroll
        for (int py = 0; py < 2; ++py)
#pragma unroll
          for (int px = 0; px < 2; ++px) {
            float f = win[py + dy][px + dx];
            acc[0][py * 2 + px] += f * w0;
            acc[1][py * 2 + px] += f * w1_;
            acc[2][py * 2 + px] += f * w2;
            acc[3][py * 2 + px] += f * w3;
          }
      }
  }
  float val[4][4];
#pragma unroll
  for (int j = 0; j < 4; ++j) {
    float bj = eb[e_s * 16 + q * 4 + j];  // uniform -> s_load
#pragma unroll
    for (int pp = 0; pp < 4; ++pp) {
      float v = acc[j][pp] + bj;
      v = v > 0.f ? v : 0.f;
      val[j][pp] = SCALE * v;
    }
  }
  if constexpr (!TAIL) {
    float* ho = h + (size_t)b * 4096;  // in-place: own sample fully read above
#pragma unroll
    for (int j = 0; j < 4; ++j) {
      int co = q * 4 + j;
#pragma unroll
      for (int dy = 0; dy < 2; ++dy)
        *(float2*)&ho[co * 256 + (2 * ty + dy) * 16 + 2 * tx] =
            make_float2(val[j][dy * 2 + 0], val[j][dy * 2 + 1]);
    }
  } else {
    // -------- fused tail: h->LDS, last conv, pool, fc1, fc2 ----------------
    __shared__ float pool[128];
    __shared__ float f1v[16];
    __shared__ float fred[16][8];
    __syncthreads();  // all window reads of old h done
#pragma unroll
    for (int j = 0; j < 4; ++j) {
      int co = q * 4 + j;
#pragma unroll
      for (int dy = 0; dy < 2; ++dy)
#pragma unroll
        for (int dx = 0; dx < 2; ++dx)
          lh[co * 324 + (2 * ty + dy + 1) * 18 + (2 * tx + dx + 1)] =
              val[j][dy * 2 + dx];
    }
    __syncthreads();
    // last conv 16->8 s2 p1: thread = (co-pair cop, out pixel oy,ox)
    const int cop = q;  // reuse readfirstlane'd t>>6
    const int oy = (t & 63) >> 3, ox = t & 7;
    float a2[2] = {0.f, 0.f};
#pragma unroll
    for (int ci = 0; ci < 16; ++ci) {
      const float* base2 = &lh[ci * 324 + (2 * oy) * 18 + 2 * ox];
      const float* wb2 = lwt + ci * 72 + cop * 2;  // uniform
      float w33[9];
#pragma unroll
      for (int dy = 0; dy < 3; ++dy) {
        float2 a = *(const float2*)&base2[dy * 18];
        w33[dy * 3 + 0] = a.x; w33[dy * 3 + 1] = a.y;
        w33[dy * 3 + 2] = base2[dy * 18 + 2];
      }
#pragma unroll
      for (int k = 0; k < 9; ++k) {
        float f = w33[k];
        a2[0] += f * wb2[k * 8 + 0];
        a2[1] += f * wb2[k * 8 + 1];
      }
    }
    // ReLU + 2x2 maxpool via shuffles (lane = oy*8+ox): ^1 -> ox, ^8 -> oy
#pragma unroll
    for (int j = 0; j < 2; ++j) {
      int co = cop * 2 + j;
      float v = a2[j] + lbg[co];  // uniform -> s_load
      v = v > 0.f ? v : 0.f;
      float m = fmaxf(v, __shfl_xor(v, 1));
      m = fmaxf(m, __shfl_xor(m, 8));
      if (((oy | ox) & 1) == 0) pool[co * 16 + (oy >> 1) * 4 + (ox >> 1)] = m;
    }
    __syncthreads();
    if (t < 128) {  // fc1: 16 rows x 8 segments of 16
      const int r = t & 15, sg = t >> 4;
      const float* wr = f1w + r * 128 + sg * 16;
      const float* pp = pool + sg * 16;
      float a = 0.f;
#pragma unroll
      for (int j = 0; j < 16; ++j) a += pp[j] * wr[j];
      fred[r][sg] = a;
    }
    __syncthreads();
    if (t < 16) {
      float a = f1b[t];
#pragma unroll
      for (int sg = 0; sg < 8; ++sg) a += fred[t][sg];
      f1v[t] = a > 0.f ? a : 0.f;
    }
    __syncthreads();
    if (t < 10) {
      float a = f2b[t];
#pragma unroll
      for (int j = 0; j < 16; ++j) a += f1v[j] * f2w[t * 16 + j];
      out[(size_t)b * 10 + t] = a;
    }
  }
}

extern "C" void kernel_launch(void* const* d_in, const int* in_sizes, int n_in,
                              void* d_out, int out_size, void* d_ws, size_t ws_size,
                              hipStream_t stream) {
  const float* x   = (const float*)d_in[0];
  const float* w1  = (const float*)d_in[1];
  const float* b1  = (const float*)d_in[2];
  const float* ew  = (const float*)d_in[3];
  const float* eb  = (const float*)d_in[4];
  const float* gw  = (const float*)d_in[5];
  const float* lwg = (const float*)d_in[6];
  const float* lbg = (const float*)d_in[7];
  const float* f1w = (const float*)d_in[8];
  const float* f1b = (const float*)d_in[9];
  const float* f2w = (const float*)d_in[10];
  const float* f2b = (const float*)d_in[11];

  float* hA  = (float*)d_ws;                    // 8192*4096 fp32 = 128 MiB
  float* w1t = hA + (size_t)8192 * 4096;        // 432
  float* ewt = w1t + 432;                       // 13824
  float* lwt = ewt + 13824;                     // 1152
  float* outp = (float*)d_out;

  k_prep<<<1, 256, 0, stream>>>(w1, ew, lwg, w1t, ewt, lwt);
  k_first<<<8192, 256, 0, stream>>>(x, w1t, b1, hA);
  for (int it = 0; it < 3; ++it)
    k_route_t<false><<<8192, 256, 0, stream>>>(hA, gw, ewt, eb, lwt, lbg,
                                               f1w, f1b, f2w, f2b, outp);
  k_route_t<true><<<8192, 256, 0, stream>>>(hA, gw, ewt, eb, lwt, lbg,
                                            f1w, f1b, f2w, f2b, outp);
}